// Round 4
// baseline (192.494 us; speedup 1.0000x reference)
//
#include <hip/hip_runtime.h>
#include <cstddef>
#include <math.h>

// Faithful float32 replication of a numpy evaluation of the reference graph.
// Every numerically-amplifying stage (bucket sums -> softmax -> einsum carry
// chain) mimics numpy's op order and rounding:
//   - bucket sums: sequential in byte order (BLAS gemv/gemm k-loop)
//   - softmax: t = x*100 rounded first; max-subtract; exp (correctly rounded
//     via f64); numpy pairwise-16 sum; true f32 division
//   - nibble_add einsum: per-output accumulation in (i,j,k) lex order with
//     w[i,j,k] = fl(fl(x_i*y_j)*c_k)  (contract(off) so no fma fusion)
// Output from_nibbles stage is separable (outer product) — deviation there is
// un-amplified (~3e-6).

__device__ __forceinline__ float exf(float t) {
  return (float)exp((double)t);  // correctly-rounded f32 exp
}

// softmax(comb * 100) with numpy rounding/order. comb: 16 raw logits.
__device__ __forceinline__ void softmax16_np(const float* comb, float* p) {
#pragma clang fp contract(off)
  float t[16];
#pragma unroll
  for (int j = 0; j < 16; ++j) t[j] = comb[j] * 100.0f;  // scale FIRST (rounded)
  float m = t[0];
#pragma unroll
  for (int j = 1; j < 16; ++j) m = fmaxf(m, t[j]);
  float e[16];
#pragma unroll
  for (int j = 0; j < 16; ++j) e[j] = exf(t[j] - m);
  // numpy pairwise sum, n=16
  float r0 = e[0] + e[8], r1 = e[1] + e[9], r2 = e[2] + e[10], r3 = e[3] + e[11];
  float r4 = e[4] + e[12], r5 = e[5] + e[13], r6 = e[6] + e[14], r7 = e[7] + e[15];
  float s = ((r0 + r1) + (r2 + r3)) + ((r4 + r5) + (r6 + r7));
#pragma unroll
  for (int j = 0; j < 16; ++j) p[j] = e[j] / s;  // true division
}

// Soft nibble add, einsum-faithful. px,py: probs; c0,c1: carry probs.
// ps <- softmax(s*100); (n0,n1) <- softmax(carry*100).
__device__ __forceinline__ void nibble_add_np(const float* px, const float* py,
                                              float c0, float c1,
                                              float* ps, float& n0, float& n1) {
#pragma clang fp contract(off)
  float s[16];
  float ca = 0.f, cb = 0.f;
#pragma unroll
  for (int l = 0; l < 16; ++l) s[l] = 0.f;
#pragma unroll
  for (int i = 0; i < 16; ++i) {
#pragma unroll
    for (int j = 0; j < 16; ++j) {
      float wij = px[i] * py[j];   // rounded, as numpy materializes x*y
      float w0 = wij * c0;         // k=0 slice (rounded)
      float w1 = wij * c1;         // k=1 slice (rounded)
      const int t0 = i + j, t1 = i + j + 1;  // compile-time after unroll
      s[t0 & 15] += w0;
      if (t0 < 16) ca += w0; else cb += w0;
      s[t1 & 15] += w1;
      if (t1 < 16) ca += w1; else cb += w1;
    }
  }
  softmax16_np(s, ps);
  float t0 = ca * 100.0f, t1 = cb * 100.0f;
  float m = fmaxf(t0, t1);
  float e0 = exf(t0 - m), e1 = exf(t1 - m);
  float ss = e0 + e1;
  n0 = e0 / ss;
  n1 = e1 / ss;
}

// x @ b2n bucket sums: strictly sequential in byte index k (BLAS k-loop order).
__device__ __forceinline__ void buckets_np(const float* __restrict__ row,
                                           float* hi, float* lo) {
#pragma clang fp contract(off)
#pragma unroll
  for (int j = 0; j < 16; ++j) { hi[j] = 0.f; lo[j] = 0.f; }
#pragma unroll
  for (int k4 = 0; k4 < 64; ++k4) {
    float4 x = *(const float4*)(row + k4 * 4);
    const int h = k4 >> 2, l0 = (k4 & 3) * 4;
    hi[h] += x.x;  hi[h] += x.y;  hi[h] += x.z;  hi[h] += x.w;  // sequential
    lo[l0 + 0] += x.x;
    lo[l0 + 1] += x.y;
    lo[l0 + 2] += x.z;
    lo[l0 + 3] += x.w;
  }
}

extern "C" __global__ void __launch_bounds__(64, 1)
byteadd_kernel(const float* __restrict__ A, const float* __restrict__ Bm,
               float* __restrict__ O, int nbatch) {
#pragma clang fp contract(off)
  const int b = blockIdx.x * 64 + threadIdx.x;
  if (b >= nbatch) return;
  const float* Ab = A + (size_t)b * 1024;
  const float* Bb = Bm + (size_t)b * 1024;
  float* Ob = O + (size_t)b * 1024;

  // Reference quirk: initial carry [1.0] broadcasts to BOTH carry slots.
  float cr0 = 1.0f, cr1 = 1.0f;

#pragma unroll 1  // keep code size bounded; carry chain is serial anyway
  for (int i = 0; i < 4; ++i) {
    float ah[16], al[16], bh[16], bl[16];
    buckets_np(Ab + i * 256, ah, al);
    buckets_np(Bb + i * 256, bh, bl);
    float pah[16], pal[16], pbh[16], pbl[16];
    softmax16_np(ah, pah);
    softmax16_np(al, pal);
    softmax16_np(bh, pbh);
    softmax16_np(bl, pbl);

    float psl[16], psh[16], d0, d1;
    nibble_add_np(pal, pbl, cr0, cr1, psl, d0, d1);   // low add, carry in
    nibble_add_np(pah, pbh, d0, d1, psh, cr0, cr1);   // high add, carry -> next

    // from_nibbles (output stage, separable)
    float ph2[16], pl2[16];
    softmax16_np(psh, ph2);
    softmax16_np(psl, pl2);

#pragma unroll
    for (int k4 = 0; k4 < 64; ++k4) {
      const int h = k4 >> 2, l0 = (k4 & 3) * 4;
      const float ph = ph2[h];
      float4 o;
      o.x = ph * pl2[l0 + 0];
      o.y = ph * pl2[l0 + 1];
      o.z = ph * pl2[l0 + 2];
      o.w = ph * pl2[l0 + 3];
      *(float4*)(Ob + i * 256 + k4 * 4) = o;
    }
  }
}

extern "C" void kernel_launch(void* const* d_in, const int* in_sizes, int n_in,
                              void* d_out, int out_size, void* d_ws, size_t ws_size,
                              hipStream_t stream) {
  const float* A = (const float*)d_in[0];
  const float* B = (const float*)d_in[1];
  float* O = (float*)d_out;
  int nbatch = in_sizes[0] / 1024;           // [B,4,256] -> B
  int blocks = (nbatch + 63) / 64;           // B=32768 -> 512 blocks
  byteadd_kernel<<<dim3(blocks), dim3(64), 0, stream>>>(A, B, O, nbatch);
}